// Round 3
// baseline (135.148 us; speedup 1.0000x reference)
//
#include <hip/hip_runtime.h>

static constexpr int   Bn      = 32;
static constexpr int   Tn      = 2000;
static constexpr int   Hn      = 512;
static constexpr int   Ln      = 256;     // max_label_len
static constexpr float kThresh = 0.95f;
static constexpr int   TCHUNK  = 40;
static constexpr int   NTCH    = Tn / TCHUNK;   // 50

// ---------------------------------------------------------------------------
// Phase 1: per-batch-row sequential integrate-and-fire scan. Bit-exact f32
// replay of the reference recurrence (same op order -> identical fire bits).
// Alpha loads are double-buffered in registers (chunks of 40 = 10x float4).
// Workspace is TIME-MAJOR (w12[t*32+b], seg[t*32+b]) so the 32 lanes store
// to consecutive addresses -> coalesced (R2's batch-major layout scattered
// every store across 32 cache lines = ~100 cyc/step).
// ---------------------------------------------------------------------------
__global__ __launch_bounds__(64) void cif_scan_kernel(
    const float* __restrict__ alphas,
    float2* __restrict__ w12,      // [Tn][Bn]
    int* __restrict__ seg,         // [Tn][Bn]
    int* __restrict__ fcnt) {      // [Bn]
  const int b = threadIdx.x;
  if (b >= Bn) return;
  const float4* __restrict__ arow =
      reinterpret_cast<const float4*>(alphas + (size_t)b * Tn);

  constexpr int CH  = 40;        // timesteps per chunk
  constexpr int CV  = CH / 4;    // 10 float4 per chunk
  constexpr int NCH = Tn / CH;   // 50

  float integrate = 0.0f;
  int   fc        = 0;

  float4 cur[CV], nxt[CV];
#pragma unroll
  for (int i = 0; i < CV; ++i) cur[i] = arow[i];

  for (int c = 0; c < NCH; ++c) {
    const bool more = (c + 1 < NCH);
    if (more) {
#pragma unroll
      for (int i = 0; i < CV; ++i) nxt[i] = arow[(size_t)(c + 1) * CV + i];
    }
    const int tbase = c * CH;
#pragma unroll
    for (int i = 0; i < CV; ++i) {
      const float a4[4] = {cur[i].x, cur[i].y, cur[i].z, cur[i].w};
#pragma unroll
      for (int j = 0; j < 4; ++j) {
        const int t     = tbase + i * 4 + j;
        const float a   = a4[j];
        const float integ = integrate + a;      // reference op order
        const bool  fire  = integ > kThresh;
        const float comp  = 1.0f - integrate;   // dist_completion
        const float cw    = fire ? comp : a;
        const float rem   = fire ? (a - cw) : 0.0f;
        w12[(size_t)t * Bn + b] = make_float2(cw, rem);  // coalesced
        seg[(size_t)t * Bn + b] = fc;                    // coalesced
        integrate = fire ? (integ - 1.0f) : integ;
        fc += fire ? 1 : 0;
      }
    }
    if (more) {
#pragma unroll
      for (int i = 0; i < CV; ++i) cur[i] = nxt[i];
    }
  }
  fcnt[b] = fc;
}

// ---------------------------------------------------------------------------
// Phase 2: segmented weighted accumulation of hidden into output frames.
// Grid (B, NTCH) x 128 threads; each thread owns 4 consecutive floats of the
// H=512 row (coalesced float4). Segments are monotone in t: accumulate in
// registers, flush on close. Only the chunk's FIRST segment (may receive the
// previous chunk's tail) and the final OPEN segment are shared -> atomicAdd;
// interior segments are exclusive -> plain float4 store (out pre-zeroed).
// w12/seg reads are block-uniform broadcasts from the L2-resident workspace.
// ---------------------------------------------------------------------------
__global__ __launch_bounds__(128) void cif_accum_kernel(
    const float* __restrict__ hidden,
    const float2* __restrict__ w12,   // [Tn][Bn]
    const int* __restrict__ seg,      // [Tn][Bn]
    const int* __restrict__ fcnt,
    float* __restrict__ out) {
  const int b   = blockIdx.x;
  const int tc  = blockIdx.y;
  const int t0  = tc * TCHUNK;
  const int t1  = t0 + TCHUNK;
  const int col = threadIdx.x * 4;

  const int fb    = fcnt[b];
  const int limit = fb < Ln ? fb : Ln;   // segments >= limit are never emitted

  const float* hbase = hidden + (size_t)b * Tn * Hn + col;
  float*       obase = out    + (size_t)b * Ln * Hn + col;

  const int seg0 = seg[(size_t)t0 * Bn + b];

  float4 acc    = make_float4(0.f, 0.f, 0.f, 0.f);
  int    curseg = seg0;

  auto flush = [&](int sg, float4 v, bool shared) {
    if (sg < limit) {
      float* o = obase + (size_t)sg * Hn;
      if (shared) {
        atomicAdd(o + 0, v.x);
        atomicAdd(o + 1, v.y);
        atomicAdd(o + 2, v.z);
        atomicAdd(o + 3, v.w);
      } else {
        *reinterpret_cast<float4*>(o) = v;   // exclusive: plain store
      }
    }
  };

  for (int t = t0; t < t1; ++t) {
    const int s = seg[(size_t)t * Bn + b];
    if (s != curseg) {               // fire with exactly-zero remainder
      flush(curseg, acc, curseg == seg0);
      acc    = make_float4(0.f, 0.f, 0.f, 0.f);
      curseg = s;
    }
    const float4 h = *reinterpret_cast<const float4*>(hbase + (size_t)t * Hn);
    const float2 w = w12[(size_t)t * Bn + b];
    acc.x += w.x * h.x;
    acc.y += w.x * h.y;
    acc.z += w.x * h.z;
    acc.w += w.x * h.w;
    if (w.y != 0.0f) {               // fire: close segment s, open s+1
      flush(s, acc, s == seg0);
      acc.x  = w.y * h.x;
      acc.y  = w.y * h.y;
      acc.z  = w.y * h.z;
      acc.w  = w.y * h.w;
      curseg = s + 1;
    }
  }
  flush(curseg, acc, true);          // open segment: may continue next chunk
}

extern "C" void kernel_launch(void* const* d_in, const int* in_sizes, int n_in,
                              void* d_out, int out_size, void* d_ws, size_t ws_size,
                              hipStream_t stream) {
  const float* hidden = (const float*)d_in[0];
  const float* alphas = (const float*)d_in[1];
  float* out = (float*)d_out;

  // ws layout: w12[T][B] float2 (512 KB) | seg[T][B] i32 (256 KB) | fcnt[B]
  float2* w12  = (float2*)d_ws;
  int*    segp = (int*)(w12 + (size_t)Bn * Tn);
  int*    fcnt = segp + (size_t)Bn * Tn;

  // Output must be zero (harness poisons with 0xAA; non-fired slots stay 0).
  hipMemsetAsync(d_out, 0, (size_t)out_size * sizeof(float), stream);

  cif_scan_kernel<<<1, 64, 0, stream>>>(alphas, w12, segp, fcnt);

  dim3 grid(Bn, NTCH);
  cif_accum_kernel<<<grid, 128, 0, stream>>>(hidden, w12, segp, fcnt, out);
}

// Round 4
// 88.824 us; speedup vs baseline: 1.5215x; 1.5215x over previous
//
#include <hip/hip_runtime.h>

static constexpr int   Bn      = 32;
static constexpr int   Tn      = 2000;
static constexpr int   Hn      = 512;
static constexpr int   Ln      = 256;     // max_label_len
static constexpr float kThresh = 0.95f;
static constexpr int   TCHUNK  = 40;
static constexpr int   NTCH    = Tn / TCHUNK;   // 50

// ---------------------------------------------------------------------------
// Phase 1: per-row sequential integrate-and-fire scan, one block (one wave)
// per batch row so the 32 serial chains run on 32 different CUs. The loop
// body is a pure register chain (add -> cmp -> cndmask, ~12 cyc/step); the
// ONLY memory traffic is the alpha loads (double-buffered, uniform across
// lanes) and one 8 B store per 40-step chunk: the exact f32 (integrate, fc)
// state at the chunk boundary. R2/R3 lesson: per-step stores force vmcnt
// waits inside the serial loop (~100+ cyc/step) — so store almost nothing.
// ---------------------------------------------------------------------------
__global__ __launch_bounds__(64) void cif_scan_kernel(
    const float* __restrict__ alphas,
    float2* __restrict__ meta,     // [Bn][NTCH]: (integrate, bits(fc)) at chunk start
    int* __restrict__ fcnt) {      // [Bn]
  const int b = blockIdx.x;
  const float4* __restrict__ arow =
      reinterpret_cast<const float4*>(alphas + (size_t)b * Tn);
  constexpr int CV = TCHUNK / 4;   // 10 float4 per chunk

  float integrate = 0.0f;
  int   fc        = 0;

  float4 cur[CV], nxt[CV];
#pragma unroll
  for (int i = 0; i < CV; ++i) cur[i] = arow[i];

  for (int c = 0; c < NTCH; ++c) {
    if (c + 1 < NTCH) {
#pragma unroll
      for (int i = 0; i < CV; ++i) nxt[i] = arow[(c + 1) * CV + i];
    }
    if (threadIdx.x == 0)
      meta[b * NTCH + c] = make_float2(integrate, __int_as_float(fc));
#pragma unroll
    for (int i = 0; i < CV; ++i) {
      const float a4[4] = {cur[i].x, cur[i].y, cur[i].z, cur[i].w};
#pragma unroll
      for (int j = 0; j < 4; ++j) {
        const float a     = a4[j];
        const float integ = integrate + a;        // reference op order
        const bool  fire  = integ > kThresh;
        integrate = fire ? (integ - 1.0f) : integ;
        fc += fire ? 1 : 0;
      }
    }
#pragma unroll
    for (int i = 0; i < CV; ++i) cur[i] = nxt[i];
  }
  if (threadIdx.x == 0) fcnt[b] = fc;
}

// ---------------------------------------------------------------------------
// Phase 2: segmented weighted accumulation. Grid (B, NTCH) x 128 threads;
// each thread owns 4 consecutive floats of the H=512 row. Each block replays
// the 40-step recurrence from the BIT-EXACT chunk-start state (same f32 ops,
// same order as the reference scan -> identical fire decisions and weights).
// The replay is wave-uniform (all threads same data -> scalar branches).
// Segments are monotone in t: accumulate in registers, flush on close. Only
// the chunk's first segment (receives the previous chunk's tail) and the
// final open segment are shared -> atomicAdd; interior segments exclusive ->
// plain float4 store (out pre-zeroed). k-loop fully unrolled: all array
// indices compile-time (runtime-indexed reg arrays would go to scratch).
// ---------------------------------------------------------------------------
__global__ __launch_bounds__(128) void cif_accum_kernel(
    const float* __restrict__ hidden,
    const float* __restrict__ alphas,
    const float2* __restrict__ meta,
    const int* __restrict__ fcnt,
    float* __restrict__ out) {
  const int b   = blockIdx.x;
  const int tc  = blockIdx.y;
  const int t0  = tc * TCHUNK;
  const int col = threadIdx.x * 4;

  const int fb    = fcnt[b];
  const int limit = fb < Ln ? fb : Ln;   // segments >= limit never emitted

  const float2 m  = meta[b * NTCH + tc];
  float integrate = m.x;
  int   fcur      = __float_as_int(m.y); // pending fire index at chunk start
  const int seg0  = fcur;

  // Preload this chunk's 40 alphas (uniform across threads, L2-resident).
  const float4* __restrict__ arow =
      reinterpret_cast<const float4*>(alphas + (size_t)b * Tn + t0);
  float av[TCHUNK];
#pragma unroll
  for (int i = 0; i < TCHUNK / 4; ++i) {
    const float4 v = arow[i];
    av[4 * i + 0] = v.x; av[4 * i + 1] = v.y;
    av[4 * i + 2] = v.z; av[4 * i + 3] = v.w;
  }

  const float* hbase = hidden + (size_t)b * Tn * Hn + (size_t)t0 * Hn + col;
  float*       obase = out    + (size_t)b * Ln * Hn + col;

  float4 acc = make_float4(0.f, 0.f, 0.f, 0.f);

  auto flush = [&](int sg, const float4& v, bool shared) {
    if (sg < limit) {
      float* o = obase + (size_t)sg * Hn;
      if (shared) {
        atomicAdd(o + 0, v.x);
        atomicAdd(o + 1, v.y);
        atomicAdd(o + 2, v.z);
        atomicAdd(o + 3, v.w);
      } else {
        *reinterpret_cast<float4*>(o) = v;   // exclusive: plain store
      }
    }
  };

#pragma unroll
  for (int k = 0; k < TCHUNK; ++k) {
    const float a     = av[k];
    const float integ = integrate + a;        // reference op order
    const bool  fire  = integ > kThresh;
    const float4 h = *reinterpret_cast<const float4*>(hbase + (size_t)k * Hn);
    if (fire) {
      const float cw  = 1.0f - integrate;     // dist_completion
      const float rem = a - cw;               // remainds
      acc.x += cw * h.x; acc.y += cw * h.y;
      acc.z += cw * h.z; acc.w += cw * h.w;
      flush(fcur, acc, fcur == seg0);
      acc.x = rem * h.x; acc.y = rem * h.y;
      acc.z = rem * h.z; acc.w = rem * h.w;
      fcur += 1;
      integrate = integ - 1.0f;
    } else {
      acc.x += a * h.x; acc.y += a * h.y;
      acc.z += a * h.z; acc.w += a * h.w;
      integrate = integ;
    }
  }
  flush(fcur, acc, true);   // open segment: may continue in the next chunk
}

extern "C" void kernel_launch(void* const* d_in, const int* in_sizes, int n_in,
                              void* d_out, int out_size, void* d_ws, size_t ws_size,
                              hipStream_t stream) {
  const float* hidden = (const float*)d_in[0];
  const float* alphas = (const float*)d_in[1];
  float* out = (float*)d_out;

  // ws layout: meta[B][NTCH] float2 (12.8 KB) | fcnt[B] i32
  float2* meta = (float2*)d_ws;
  int*    fcnt = (int*)(meta + (size_t)Bn * NTCH);

  // Output must be zero (harness poisons with 0xAA; non-fired slots stay 0).
  hipMemsetAsync(d_out, 0, (size_t)out_size * sizeof(float), stream);

  cif_scan_kernel<<<Bn, 64, 0, stream>>>(alphas, meta, fcnt);

  dim3 grid(Bn, NTCH);
  cif_accum_kernel<<<grid, 128, 0, stream>>>(hidden, alphas, meta, fcnt, out);
}